// Round 1
// baseline (1191.972 us; speedup 1.0000x reference)
//
#include <hip/hip_runtime.h>
#include <hip/hip_bf16.h>

#define N_ROWS 65536
#define DIM 64
#define KC 2048
#define DECAY_F 0.99f
#define OMD_F 0.01f
#define EPS_F 1e-5f

// ws layout (floats):
static constexpr size_t WS_E2     = 0;                  // [2048]
static constexpr size_t WS_COUNTS = 2048;               // [2048]
static constexpr size_t WS_ESUM   = 4096;               // [2048*64]
static constexpr size_t WS_LOSS   = 4096 + 131072;      // [1]
static constexpr size_t WS_SMOOTH = WS_LOSS + 1;        // [2048]
static constexpr size_t WS_FLOATS = WS_SMOOTH + 2048;

__global__ void vq_e2_kernel(const float* __restrict__ embed, float* __restrict__ ws) {
    int k = blockIdx.x * blockDim.x + threadIdx.x;
    if (k >= KC) return;
    const float4* e4 = reinterpret_cast<const float4*>(embed + (size_t)k * DIM);
    float s = 0.f;
#pragma unroll
    for (int i = 0; i < DIM / 4; ++i) {
        float4 v = e4[i];
        s += v.x * v.x + v.y * v.y + v.z * v.z + v.w * v.w;
    }
    ws[WS_E2 + k] = s;
}

__global__ __launch_bounds__(256, 4) void vq_main_kernel(
    const float* __restrict__ x,
    const float* __restrict__ embed,
    float* __restrict__ ws,
    float* __restrict__ out_q,
    float* __restrict__ out_ind) {
    __shared__ float s_dist[4][64];
    __shared__ int   s_idx[4][64];

    const int lane = threadIdx.x & 63;
    const int wave = __builtin_amdgcn_readfirstlane(threadIdx.x >> 6);
    const int row  = blockIdx.x * 64 + lane;

    // Load this lane's x row into registers (64 VGPRs).
    float xr[DIM];
    {
        const float4* x4 = reinterpret_cast<const float4*>(x + (size_t)row * DIM);
#pragma unroll
        for (int i = 0; i < DIM / 4; ++i) {
            float4 v = x4[i];
            xr[4 * i + 0] = v.x; xr[4 * i + 1] = v.y;
            xr[4 * i + 2] = v.z; xr[4 * i + 3] = v.w;
        }
    }

    const float* __restrict__ e2 = ws + WS_E2;
    const int k0 = wave * (KC / 4);

    float best = __builtin_inff();
    int bidx = 0;

    for (int kk = 0; kk < KC / 4; kk += 2) {
        const int ka = k0 + kk;
        const float* __restrict__ ea = embed + (size_t)ka * DIM;
        const float* __restrict__ eb = ea + DIM;
        float a0 = 0.f, a1 = 0.f, a2 = 0.f, a3 = 0.f;
        float b0 = 0.f, b1 = 0.f, b2 = 0.f, b3 = 0.f;
#pragma unroll
        for (int d = 0; d < DIM; d += 4) {
            a0 = fmaf(xr[d + 0], ea[d + 0], a0);
            a1 = fmaf(xr[d + 1], ea[d + 1], a1);
            a2 = fmaf(xr[d + 2], ea[d + 2], a2);
            a3 = fmaf(xr[d + 3], ea[d + 3], a3);
            b0 = fmaf(xr[d + 0], eb[d + 0], b0);
            b1 = fmaf(xr[d + 1], eb[d + 1], b1);
            b2 = fmaf(xr[d + 2], eb[d + 2], b2);
            b3 = fmaf(xr[d + 3], eb[d + 3], b3);
        }
        float dota = (a0 + a1) + (a2 + a3);
        float dotb = (b0 + b1) + (b2 + b3);
        float da = fmaf(-2.f, dota, e2[ka]);
        float db = fmaf(-2.f, dotb, e2[ka + 1]);
        if (da < best) { best = da; bidx = ka; }
        if (db < best) { best = db; bidx = ka + 1; }
    }

    s_dist[wave][lane] = best;
    s_idx[wave][lane]  = bidx;
    __syncthreads();

    if (wave == 0) {
        float fbest = s_dist[0][lane];
        int   fidx  = s_idx[0][lane];
#pragma unroll
        for (int w = 1; w < 4; ++w) {
            float dw = s_dist[w][lane];
            int   iw = s_idx[w][lane];
            if (dw < fbest) { fbest = dw; fidx = iw; }
        }
        out_ind[row] = (float)fidx;

        const float4* q4 = reinterpret_cast<const float4*>(embed + (size_t)fidx * DIM);
        float4* o4 = reinterpret_cast<float4*>(out_q + (size_t)row * DIM);
        float* esum = ws + WS_ESUM + (size_t)fidx * DIM;
        float loss = 0.f;
#pragma unroll
        for (int i = 0; i < DIM / 4; ++i) {
            float4 q = q4[i];
            o4[i] = q;
            float d0 = q.x - xr[4 * i + 0]; loss = fmaf(d0, d0, loss);
            float d1 = q.y - xr[4 * i + 1]; loss = fmaf(d1, d1, loss);
            float d2 = q.z - xr[4 * i + 2]; loss = fmaf(d2, d2, loss);
            float d3 = q.w - xr[4 * i + 3]; loss = fmaf(d3, d3, loss);
            atomicAdd(&esum[4 * i + 0], xr[4 * i + 0]);
            atomicAdd(&esum[4 * i + 1], xr[4 * i + 1]);
            atomicAdd(&esum[4 * i + 2], xr[4 * i + 2]);
            atomicAdd(&esum[4 * i + 3], xr[4 * i + 3]);
        }
        atomicAdd(&ws[WS_COUNTS + fidx], 1.0f);

#pragma unroll
        for (int off = 32; off > 0; off >>= 1)
            loss += __shfl_down(loss, off, 64);
        if (lane == 0) atomicAdd(&ws[WS_LOSS], loss);
    }
}

__global__ void vq_finalize1_kernel(const float* __restrict__ cluster_size,
                                    float* __restrict__ ws,
                                    float* __restrict__ out_loss) {
    __shared__ float red[256];
    const int t = threadIdx.x;
    float partial = 0.f;
    for (int k = t; k < KC; k += 256) {
        float ncs = fmaf(OMD_F, ws[WS_COUNTS + k], DECAY_F * cluster_size[k]);
        partial += ncs;
    }
    red[t] = partial;
    __syncthreads();
    for (int s = 128; s > 0; s >>= 1) {
        if (t < s) red[t] += red[t + s];
        __syncthreads();
    }
    const float n = red[0];
    const float denom = n + (float)(KC * 1e-5);
    for (int k = t; k < KC; k += 256) {
        float ncs = fmaf(OMD_F, ws[WS_COUNTS + k], DECAY_F * cluster_size[k]);
        ws[WS_SMOOTH + k] = (ncs + EPS_F) / denom * n;
    }
    if (t == 0) out_loss[0] = ws[WS_LOSS] / (float)((size_t)N_ROWS * DIM);
}

__global__ void vq_finalize2_kernel(const float* __restrict__ embed_avg,
                                    const float* __restrict__ ws,
                                    float* __restrict__ out_embed) {
    int i = blockIdx.x * blockDim.x + threadIdx.x;
    if (i >= KC * DIM) return;
    int k = i >> 6;
    float na = fmaf(OMD_F, ws[WS_ESUM + i], DECAY_F * embed_avg[i]);
    out_embed[i] = na / ws[WS_SMOOTH + k];
}

extern "C" void kernel_launch(void* const* d_in, const int* in_sizes, int n_in,
                              void* d_out, int out_size, void* d_ws, size_t ws_size,
                              hipStream_t stream) {
    const float* x            = (const float*)d_in[0];
    const float* embed        = (const float*)d_in[1];
    const float* embed_avg    = (const float*)d_in[2];
    const float* cluster_size = (const float*)d_in[3];

    float* out      = (float*)d_out;
    float* out_q    = out;                                  // [N*D]
    float* out_loss = out + (size_t)N_ROWS * DIM;           // [1]
    float* out_ind  = out_loss + 1;                         // [N]
    float* out_emb  = out_ind + N_ROWS;                     // [K*D]

    float* ws = (float*)d_ws;

    hipMemsetAsync(ws, 0, WS_FLOATS * sizeof(float), stream);
    vq_e2_kernel<<<KC / 256, 256, 0, stream>>>(embed, ws);
    vq_main_kernel<<<N_ROWS / 64, 256, 0, stream>>>(x, embed, ws, out_q, out_ind);
    vq_finalize1_kernel<<<1, 256, 0, stream>>>(cluster_size, ws, out_loss);
    vq_finalize2_kernel<<<(KC * DIM) / 256, 256, 0, stream>>>(embed_avg, ws, out_emb);
}